// Round 1
// baseline (2928.498 us; speedup 1.0000x reference)
//
#include <hip/hip_runtime.h>

#define NCLUST 256      // clusters 1..256 (cluster 0 = CLID_UNMATCHED, excluded)
#define NFEAT  64
#define NBLK_A 512
#define BIGF   1e30f

// ---- static device scratch (avoids d_ws size uncertainty; rewritten fully every call) ----
__device__ __align__(16) float  g_partials[(size_t)NBLK_A * NCLUST * NFEAT]; // per-block f32 sums
__device__ float  g_cnt[NCLUST];          // counts (f32 atomic adds of 1.0 -> exact)
__device__ float  g_ssq[NCLUST];          // sum of squares (scalar per cluster)
__device__ __align__(16) double g_means64[NCLUST * NFEAT];
__device__ __align__(16) float  g_means32[NCLUST * NFEAT];
__device__ double g_tn64[NCLUST];
__device__ double g_std64[NCLUST];
__device__ float  g_std32[NCLUST];
__device__ float2 g_ktab[NCLUST];         // (tn_f32, thr2_f32 or -1 if invalid)
__device__ int    g_valid[NCLUST];
__device__ int    g_list[1000000];
__device__ int    g_nlist;

// ---------------- Z: zero accumulators ----------------
__global__ void kzero() {
    int t = threadIdx.x;
    if (t < NCLUST) { g_cnt[t] = 0.f; g_ssq[t] = 0.f; }
    if (t == 0) g_nlist = 0;
}

// ---------------- A: per-block segment sums into LDS, flush partials ----------------
__global__ __launch_bounds__(256) void kstats(const float* __restrict__ spikes,
                                              const int* __restrict__ sidx, int n) {
    __shared__ float lsum[NCLUST * NFEAT]; // exactly 64 KiB
    for (int idx = threadIdx.x; idx < NCLUST * NFEAT; idx += 256) lsum[idx] = 0.f;
    __syncthreads();

    const int lane = threadIdx.x & 63;
    const int wave = threadIdx.x >> 6;
    const int per  = (n + gridDim.x - 1) / gridDim.x;
    const int s0   = blockIdx.x * per;
    const int s1   = min(n, s0 + per);

    for (int ib = s0 + wave * 4; ib < s1; ib += 16) {
        float vv[4]; int cc[4];
        #pragma unroll
        for (int j = 0; j < 4; ++j) {
            int i = ib + j;
            bool ok = (i < s1);                       // wave-uniform
            vv[j] = ok ? spikes[(size_t)i * NFEAT + lane] : 0.f;
            cc[j] = ok ? sidx[i] : 0;
        }
        #pragma unroll
        for (int j = 0; j < 4; ++j) {
            float v = vv[j]; int c = cc[j];
            float w = v * v;
            #pragma unroll
            for (int o = 32; o; o >>= 1) w += __shfl_xor(w, o);
            if (c != 0) {
                atomicAdd(&lsum[(c - 1) * NFEAT + lane], v);
                if (lane == 0) {
                    atomicAdd(&g_ssq[c - 1], w);
                    atomicAdd(&g_cnt[c - 1], 1.0f);
                }
            }
        }
    }
    __syncthreads();
    size_t base = (size_t)blockIdx.x * (NCLUST * NFEAT);
    for (int idx = threadIdx.x; idx < NCLUST * NFEAT; idx += 256)
        g_partials[base + idx] = lsum[idx];
}

// ---------------- A2: deterministic f64 reduce -> means / tn / std ----------------
__global__ __launch_bounds__(256) void kfinal() {
    const int c = blockIdx.x;                 // cluster c+1
    __shared__ double red[4][NFEAT];
    __shared__ double smean[NFEAT];
    const int f = threadIdx.x & 63, j = threadIdx.x >> 6;

    double acc = 0.0;
    for (int b = j; b < NBLK_A; b += 4)
        acc += (double)g_partials[(size_t)b * (NCLUST * NFEAT) + c * NFEAT + f];
    red[j][f] = acc;
    __syncthreads();

    if (threadIdx.x < NFEAT) {
        double s = ((red[0][f] + red[1][f]) + red[2][f]) + red[3][f];
        float cnt = g_cnt[c];
        double mean = (cnt > 0.f) ? s / (double)cnt : 0.0;
        g_means64[c * NFEAT + f] = mean;
        g_means32[c * NFEAT + f] = (float)mean;
        smean[f] = mean;
    }
    __syncthreads();
    if (threadIdx.x == 0) {
        double tn = 0.0;
        for (int q = 0; q < NFEAT; ++q) tn += smean[q] * smean[q];
        float cnt = g_cnt[c];
        double var = (cnt > 0.f) ? (double)g_ssq[c] / (double)cnt - tn : 0.0;
        if (var < 0.0) var = 0.0;
        double sd = sqrt(var);
        g_tn64[c] = tn; g_std64[c] = sd; g_std32[c] = (float)sd;
    }
}

// ---------------- A3: median of valid stds, validity, thresholds ----------------
__global__ __launch_bounds__(256) void kmedian() {
    __shared__ float svals[NCLUST];
    __shared__ int   svalid[NCLUST];
    __shared__ float mred[2];
    int t = threadIdx.x;
    if (t == 0) { mred[0] = 0.f; mred[1] = 0.f; }
    float cnt = g_cnt[t];
    int v0 = (cnt > 0.f) ? 1 : 0;
    float sd = g_std32[t];
    svals[t] = sd; svalid[t] = v0;
    __syncthreads();

    int m = 0, rank = 0;
    for (int jj = 0; jj < NCLUST; ++jj) {
        if (svalid[jj]) {
            ++m;
            float sj = svals[jj];
            if (sj < sd || (sj == sd && jj < t)) ++rank;
        }
    }
    if (v0) {
        if (rank == (m - 1) / 2) mred[0] = sd;
        if (rank == m / 2)       mred[1] = sd;
    }
    __syncthreads();
    float med = 0.5f * (mred[0] + mred[1]);

    int valid = v0 && (sd <= 3.0f * med);
    double sd64 = g_std64[t];
    float thr2 = valid ? (float)((1.5 * sd64) * (1.5 * sd64)) : -1.0f;
    g_valid[t] = valid;
    g_ktab[t]  = make_float2((float)g_tn64[t], thr2);
}

// ---------------- C: bulk min pass (all rows) + default outputs + unmatched list ----------------
__global__ __launch_bounds__(256) void kdist(const float* __restrict__ spikes,
                                             const int* __restrict__ sidx,
                                             const unsigned char* __restrict__ midx,
                                             float* __restrict__ out, int n) {
    __shared__ __align__(16) float lm[NCLUST * NFEAT]; // 64 KiB templates
    for (int idx = threadIdx.x * 4; idx < NCLUST * NFEAT; idx += 256 * 4)
        *(float4*)&lm[idx] = *(const float4*)&g_means32[idx];
    __syncthreads();

    int i = blockIdx.x * 256 + threadIdx.x;
    if (i >= n) return;

    float s[NFEAT];
    const float4* sp = (const float4*)(spikes + (size_t)i * NFEAT);
    #pragma unroll
    for (int q = 0; q < 16; ++q) *(float4*)&s[q * 4] = sp[q];

    float sn = 0.f;
    #pragma unroll
    for (int f = 0; f < NFEAT; ++f) sn = fmaf(s[f], s[f], sn);

    float d2min = 3.4e38f;
    bool  any   = false;
    for (int k = 0; k < NCLUST; ++k) {
        float2 kt = g_ktab[k];
        float a0 = 0.f, a1 = 0.f, a2 = 0.f, a3 = 0.f;
        const float* mk = &lm[k * NFEAT];
        #pragma unroll
        for (int f = 0; f < NFEAT; f += 4) {
            a0 = fmaf(s[f + 0], mk[f + 0], a0);
            a1 = fmaf(s[f + 1], mk[f + 1], a1);
            a2 = fmaf(s[f + 2], mk[f + 2], a2);
            a3 = fmaf(s[f + 3], mk[f + 3], a3);
        }
        float dot = (a0 + a1) + (a2 + a3);
        float d2 = (sn - 2.0f * dot) + kt.x;
        if (!(d2 > kt.y)) { any = true; d2min = fminf(d2min, d2); }  // thr2=-1 => always masked
    }
    float mv = any ? sqrtf(fmaxf(d2min, 0.f)) : BIGF;

    int si = sidx[i];
    out[i]                 = (float)si;
    out[(size_t)n + i]     = midx[i] ? 1.0f : 0.0f;
    out[2 * (size_t)n + i] = mv;

    if (si == 0) {
        int p = atomicAdd(&g_nlist, 1);
        if (p < 1000000) g_list[p] = i;
    }
}

// ---------------- D: precise f64 argmin for unmatched rows ----------------
__global__ __launch_bounds__(256) void kprecise(const float* __restrict__ spikes,
                                                float* __restrict__ out, int n) {
    int nt = g_nlist;
    for (int t = blockIdx.x * blockDim.x + threadIdx.x; t < nt;
         t += gridDim.x * blockDim.x) {
        int i = g_list[t];
        double s[NFEAT]; double sn = 0.0;
        const float* sp = spikes + (size_t)i * NFEAT;
        #pragma unroll
        for (int f = 0; f < NFEAT; ++f) { s[f] = (double)sp[f]; sn += s[f] * s[f]; }

        double dmin = 1e30; int best = 0;
        for (int k = 0; k < NCLUST; ++k) {
            if (!g_valid[k]) continue;
            const double* mk = &g_means64[k * NFEAT];
            double dot = 0.0;
            #pragma unroll
            for (int f = 0; f < NFEAT; ++f) dot += s[f] * mk[f];
            double d2 = (sn - 2.0 * dot) + g_tn64[k];
            double dist = sqrt(fmax(d2, 0.0));
            if (dist > 1.5 * g_std64[k]) continue;
            if (dist < dmin) { dmin = dist; best = k + 1; }   // ascending k => first-index ties
        }
        if (dmin >= 256.0) best = 0;   // FIRST_MATCH_MAX_DIST * N_SAMPLES
        out[i]                 = (float)best;
        out[(size_t)n + i]     = (best != 0) ? 1.0f : 0.0f;
        out[2 * (size_t)n + i] = (float)dmin;
    }
}

extern "C" void kernel_launch(void* const* d_in, const int* in_sizes, int n_in,
                              void* d_out, int out_size, void* d_ws, size_t ws_size,
                              hipStream_t stream) {
    const float*         spikes = (const float*)d_in[0];
    const int*           sidx   = (const int*)d_in[1];
    const unsigned char* midx   = (const unsigned char*)d_in[2];
    float*               out    = (float*)d_out;
    const int n = in_sizes[1];

    kzero<<<1, 256, 0, stream>>>();
    kstats<<<NBLK_A, 256, 0, stream>>>(spikes, sidx, n);
    kfinal<<<NCLUST, 256, 0, stream>>>();
    kmedian<<<1, 256, 0, stream>>>();
    int nblk = (n + 255) / 256;
    kdist<<<nblk, 256, 0, stream>>>(spikes, sidx, midx, out, n);
    kprecise<<<64, 256, 0, stream>>>(spikes, out, n);
}

// Round 2
// 1093.776 us; speedup vs baseline: 2.6774x; 2.6774x over previous
//
#include <hip/hip_runtime.h>

#define NCLUST 256      // clusters 1..256 (cluster 0 = CLID_UNMATCHED, excluded)
#define NFEAT  64
#define NBLK_A 512
#define BIGF   1e30f

typedef __attribute__((ext_vector_type(8))) short  short8v;   // 8 x bf16
typedef __attribute__((ext_vector_type(4))) float  float4v;

// ---- static device scratch (rewritten fully every call) ----
__device__ __align__(16) float  g_partials[(size_t)NBLK_A * NCLUST * NFEAT]; // per-block f32 sums
__device__ float  g_pcnt[NBLK_A * NCLUST];
__device__ float  g_pssq[NBLK_A * NCLUST];
__device__ float  g_cnt[NCLUST];
__device__ __align__(16) double g_means64[NCLUST * NFEAT];
__device__ __align__(16) float  g_means32[NCLUST * NFEAT];
__device__ double g_tn64[NCLUST];
__device__ double g_std64[NCLUST];
__device__ float  g_std32[NCLUST];
__device__ float2 g_ktab[NCLUST];         // (tn_f32, thr2_f32 or -1 if invalid)
__device__ int    g_valid[NCLUST];
__device__ int    g_list[1000000];
__device__ int    g_nlist;

static __device__ __forceinline__ unsigned short f2bf(float x) {
    union { float f; unsigned u; } v; v.f = x;
    unsigned r = v.u + 0x7fffu + ((v.u >> 16) & 1u);   // RNE
    return (unsigned short)(r >> 16);
}

// ---------------- Z ----------------
__global__ void kzero() { if (threadIdx.x == 0) g_nlist = 0; }

// ---------------- A: per-block segment sums, NO global atomics ----------------
__global__ __launch_bounds__(256) void kstats(const float* __restrict__ spikes,
                                              const int* __restrict__ sidx, int n) {
    __shared__ float lsum[NCLUST * NFEAT]; // 64 KiB
    __shared__ float lcnt[NCLUST];
    __shared__ float lssq[NCLUST];
    for (int idx = threadIdx.x; idx < NCLUST * NFEAT; idx += 256) lsum[idx] = 0.f;
    if (threadIdx.x < NCLUST) { lcnt[threadIdx.x] = 0.f; lssq[threadIdx.x] = 0.f; }
    __syncthreads();

    const int lane = threadIdx.x & 63;
    const int wave = threadIdx.x >> 6;
    const int per  = (n + gridDim.x - 1) / gridDim.x;
    const int s0   = blockIdx.x * per;
    const int s1   = min(n, s0 + per);

    for (int ib = s0 + wave * 8; ib < s1; ib += 32) {
        float vv[8]; int cc[8];
        #pragma unroll
        for (int j = 0; j < 8; ++j) {
            int i = ib + j;
            bool ok = (i < s1);                       // wave-uniform
            vv[j] = ok ? spikes[(size_t)i * NFEAT + lane] : 0.f;
            cc[j] = ok ? sidx[i] : 0;
        }
        #pragma unroll
        for (int j = 0; j < 8; ++j) {
            float v = vv[j]; int c = cc[j];
            float w = v * v;
            #pragma unroll
            for (int o = 32; o; o >>= 1) w += __shfl_xor(w, o);
            if (c != 0) {
                atomicAdd(&lsum[(c - 1) * NFEAT + lane], v);
                if (lane == 0) {
                    atomicAdd(&lssq[c - 1], w);
                    atomicAdd(&lcnt[c - 1], 1.0f);
                }
            }
        }
    }
    __syncthreads();
    size_t base = (size_t)blockIdx.x * (NCLUST * NFEAT);
    for (int idx = threadIdx.x; idx < NCLUST * NFEAT; idx += 256)
        g_partials[base + idx] = lsum[idx];
    if (threadIdx.x < NCLUST) {
        g_pcnt[blockIdx.x * NCLUST + threadIdx.x] = lcnt[threadIdx.x];
        g_pssq[blockIdx.x * NCLUST + threadIdx.x] = lssq[threadIdx.x];
    }
}

// ---------------- A2: deterministic f64 reduce -> means / cnt / ssq / tn / std ----------------
__global__ __launch_bounds__(256) void kfinal() {
    const int c = blockIdx.x;                 // cluster c+1
    __shared__ double red[4][NFEAT];
    __shared__ double smean[NFEAT];
    __shared__ double sh_cnt, sh_ssq;
    const int f = threadIdx.x & 63, j = threadIdx.x >> 6;

    double acc = 0.0;
    for (int b = j; b < NBLK_A; b += 4)
        acc += (double)g_partials[(size_t)b * (NCLUST * NFEAT) + c * NFEAT + f];
    red[j][f] = acc;

    // cnt/ssq reduce on wave 0 (deterministic tree)
    if (threadIdx.x < 64) {
        double ca = 0.0, sa = 0.0;
        for (int b = threadIdx.x; b < NBLK_A; b += 64) {
            ca += (double)g_pcnt[b * NCLUST + c];
            sa += (double)g_pssq[b * NCLUST + c];
        }
        #pragma unroll
        for (int o = 32; o; o >>= 1) {
            ca += __shfl_xor(ca, o);
            sa += __shfl_xor(sa, o);
        }
        if (threadIdx.x == 0) { sh_cnt = ca; sh_ssq = sa; }
    }
    __syncthreads();

    if (threadIdx.x < NFEAT) {
        double s = ((red[0][f] + red[1][f]) + red[2][f]) + red[3][f];
        double cnt = sh_cnt;
        double mean = (cnt > 0.0) ? s / cnt : 0.0;
        g_means64[c * NFEAT + f] = mean;
        g_means32[c * NFEAT + f] = (float)mean;
        smean[f] = mean;
    }
    __syncthreads();
    if (threadIdx.x == 0) {
        double tn = 0.0;
        for (int q = 0; q < NFEAT; ++q) tn += smean[q] * smean[q];
        double cnt = sh_cnt;
        double var = (cnt > 0.0) ? sh_ssq / cnt - tn : 0.0;
        if (var < 0.0) var = 0.0;
        double sd = sqrt(var);
        g_tn64[c] = tn; g_std64[c] = sd; g_std32[c] = (float)sd;
        g_cnt[c] = (float)cnt;
    }
}

// ---------------- A3: median of valid stds, validity, thresholds ----------------
__global__ __launch_bounds__(256) void kmedian() {
    __shared__ float svals[NCLUST];
    __shared__ int   svalid[NCLUST];
    __shared__ float mred[2];
    int t = threadIdx.x;
    if (t == 0) { mred[0] = 0.f; mred[1] = 0.f; }
    float cnt = g_cnt[t];
    int v0 = (cnt > 0.f) ? 1 : 0;
    float sd = g_std32[t];
    svals[t] = sd; svalid[t] = v0;
    __syncthreads();

    int m = 0, rank = 0;
    for (int jj = 0; jj < NCLUST; ++jj) {
        if (svalid[jj]) {
            ++m;
            float sj = svals[jj];
            if (sj < sd || (sj == sd && jj < t)) ++rank;
        }
    }
    if (v0) {
        if (rank == (m - 1) / 2) mred[0] = sd;
        if (rank == m / 2)       mred[1] = sd;
    }
    __syncthreads();
    float med = 0.5f * (mred[0] + mred[1]);

    int valid = v0 && (sd <= 3.0f * med);
    double sd64 = g_std64[t];
    float thr2 = valid ? (float)((1.5 * sd64) * (1.5 * sd64)) : -1.0f;
    g_valid[t] = valid;
    g_ktab[t]  = make_float2((float)g_tn64[t], thr2);
}

// ---------------- C: MFMA bulk min pass ----------------
// Per block: 4 waves x 16 spikes = 64 spikes. Templates bf16 in LDS (32KB, XOR-swizzled).
// mfma_f32_16x16x32_bf16: A lane l -> row=l&15, k=(l>>4)*8+j ; B lane l -> col=l&15, same k map.
// D lane l, reg r -> row=(l>>4)*4+r, col=l&15  [verified layout, m89]
__global__ __launch_bounds__(256) void kmatch(const float* __restrict__ spikes,
                                              const int* __restrict__ sidx,
                                              const unsigned char* __restrict__ midx,
                                              float* __restrict__ out, int n) {
    __shared__ __align__(16) unsigned short tml[NCLUST * NFEAT]; // 32 KiB swizzled bf16
    __shared__ float2 ktab_sh[NCLUST];

    // stage templates: chunk q = (c,g), 8 bf16 per chunk, swizzled byte offset
    for (int q = threadIdx.x; q < NCLUST * 8; q += 256) {
        int c = q >> 3, g = q & 7;
        float4 u0 = *(const float4*)&g_means32[c * NFEAT + g * 8];
        float4 u1 = *(const float4*)&g_means32[c * NFEAT + g * 8 + 4];
        short8v h;
        h[0] = (short)f2bf(u0.x); h[1] = (short)f2bf(u0.y);
        h[2] = (short)f2bf(u0.z); h[3] = (short)f2bf(u0.w);
        h[4] = (short)f2bf(u1.x); h[5] = (short)f2bf(u1.y);
        h[6] = (short)f2bf(u1.z); h[7] = (short)f2bf(u1.w);
        unsigned byteoff = (unsigned)c * 128u + (((unsigned)g * 16u) ^ (((unsigned)c & 7u) << 4));
        *(short8v*)((char*)tml + byteoff) = h;
    }
    if (threadIdx.x < NCLUST) ktab_sh[threadIdx.x] = g_ktab[threadIdx.x];
    __syncthreads();

    const int lane = threadIdx.x & 63, wave = threadIdx.x >> 6;
    const int row  = lane & 15, grp = lane >> 4;
    const int i0   = blockIdx.x * 64 + wave * 16;

    // ---- A fragments (spikes straight from global, f32 -> bf16) ----
    int ri = i0 + row;
    int rc = (ri < n) ? ri : (n - 1);
    const float* sp = spikes + (size_t)rc * NFEAT + grp * 8;
    float4 a0 = *(const float4*)(sp);
    float4 a1 = *(const float4*)(sp + 4);
    float4 a2 = *(const float4*)(sp + 32);
    float4 a3 = *(const float4*)(sp + 36);
    short8v af0, af1;
    af0[0] = (short)f2bf(a0.x); af0[1] = (short)f2bf(a0.y);
    af0[2] = (short)f2bf(a0.z); af0[3] = (short)f2bf(a0.w);
    af0[4] = (short)f2bf(a1.x); af0[5] = (short)f2bf(a1.y);
    af0[6] = (short)f2bf(a1.z); af0[7] = (short)f2bf(a1.w);
    af1[0] = (short)f2bf(a2.x); af1[1] = (short)f2bf(a2.y);
    af1[2] = (short)f2bf(a2.z); af1[3] = (short)f2bf(a2.w);
    af1[4] = (short)f2bf(a3.x); af1[5] = (short)f2bf(a3.y);
    af1[6] = (short)f2bf(a3.z); af1[7] = (short)f2bf(a3.w);

    // sn (|s|^2) in f32 from ORIGINAL f32 values; reduce across the 4 k-groups
    float pss = a0.x*a0.x + a0.y*a0.y + a0.z*a0.z + a0.w*a0.w
              + a1.x*a1.x + a1.y*a1.y + a1.z*a1.z + a1.w*a1.w
              + a2.x*a2.x + a2.y*a2.y + a2.z*a2.z + a2.w*a2.w
              + a3.x*a3.x + a3.y*a3.y + a3.z*a3.z + a3.w*a3.w;
    pss += __shfl_xor(pss, 16);
    pss += __shfl_xor(pss, 32);          // now sn of row `row` on every lane

    float snr[4];
    #pragma unroll
    for (int r = 0; r < 4; ++r) snr[r] = __shfl(pss, grp * 4 + r);  // sn of D-row (grp*4+r)

    float d2min[4] = {3.4e38f, 3.4e38f, 3.4e38f, 3.4e38f};

    #pragma unroll 2
    for (int nt = 0; nt < 16; ++nt) {
        int c = nt * 16 + row;
        unsigned co = (unsigned)c * 128u;
        unsigned sw = (((unsigned)c & 7u) << 4);
        short8v b0 = *(short8v*)((char*)tml + (co + (((unsigned)grp * 16u) ^ sw)));
        short8v b1 = *(short8v*)((char*)tml + (co + ((((unsigned)grp + 4u) * 16u) ^ sw)));
        float4v acc = {0.f, 0.f, 0.f, 0.f};
        acc = __builtin_amdgcn_mfma_f32_16x16x32_bf16(af0, b0, acc, 0, 0, 0);
        acc = __builtin_amdgcn_mfma_f32_16x16x32_bf16(af1, b1, acc, 0, 0, 0);
        float2 kt = ktab_sh[c];
        #pragma unroll
        for (int r = 0; r < 4; ++r) {
            float d2 = (snr[r] - 2.0f * acc[r]) + kt.x;
            if (!(d2 > kt.y)) d2min[r] = fminf(d2min[r], d2);  // thr2=-1 => always masked
        }
    }

    // min over the 16 cluster-lanes (xor 1,2,4,8)
    #pragma unroll
    for (int o = 1; o < 16; o <<= 1) {
        #pragma unroll
        for (int r = 0; r < 4; ++r) d2min[r] = fminf(d2min[r], __shfl_xor(d2min[r], o));
    }
    if (row == 0) {
        #pragma unroll
        for (int r = 0; r < 4; ++r) {
            int i = i0 + grp * 4 + r;
            if (i < n) {
                float dm = d2min[r];
                out[2 * (size_t)n + i] = (dm > 1e37f) ? BIGF : sqrtf(fmaxf(dm, 0.f));
            }
        }
    }

    // pass-through outputs + unmatched list (threads 0..63 cover this block's 64 spikes)
    if (threadIdx.x < 64) {
        int i = blockIdx.x * 64 + threadIdx.x;
        if (i < n) {
            int si = sidx[i];
            out[i]             = (float)si;
            out[(size_t)n + i] = midx[i] ? 1.0f : 0.0f;
            if (si == 0) {
                int p = atomicAdd(&g_nlist, 1);
                if (p < 1000000) g_list[p] = i;
            }
        }
    }
}

// ---------------- D: precise f64 argmin for unmatched rows ----------------
__global__ __launch_bounds__(256) void kprecise(const float* __restrict__ spikes,
                                                float* __restrict__ out, int n) {
    int nt = g_nlist;
    for (int t = blockIdx.x * blockDim.x + threadIdx.x; t < nt;
         t += gridDim.x * blockDim.x) {
        int i = g_list[t];
        double s[NFEAT]; double sn = 0.0;
        const float* sp = spikes + (size_t)i * NFEAT;
        #pragma unroll
        for (int f = 0; f < NFEAT; ++f) { s[f] = (double)sp[f]; sn += s[f] * s[f]; }

        double dmin = 1e30; int best = 0;
        for (int k = 0; k < NCLUST; ++k) {
            if (!g_valid[k]) continue;
            const double* mk = &g_means64[k * NFEAT];
            double dot = 0.0;
            #pragma unroll
            for (int f = 0; f < NFEAT; ++f) dot += s[f] * mk[f];
            double d2 = (sn - 2.0 * dot) + g_tn64[k];
            double dist = sqrt(fmax(d2, 0.0));
            if (dist > 1.5 * g_std64[k]) continue;
            if (dist < dmin) { dmin = dist; best = k + 1; }   // ascending k => first-index ties
        }
        if (dmin >= 256.0) best = 0;   // FIRST_MATCH_MAX_DIST * N_SAMPLES
        out[i]                 = (float)best;
        out[(size_t)n + i]     = (best != 0) ? 1.0f : 0.0f;
        out[2 * (size_t)n + i] = (float)dmin;
    }
}

extern "C" void kernel_launch(void* const* d_in, const int* in_sizes, int n_in,
                              void* d_out, int out_size, void* d_ws, size_t ws_size,
                              hipStream_t stream) {
    const float*         spikes = (const float*)d_in[0];
    const int*           sidx   = (const int*)d_in[1];
    const unsigned char* midx   = (const unsigned char*)d_in[2];
    float*               out    = (float*)d_out;
    const int n = in_sizes[1];

    kzero<<<1, 64, 0, stream>>>();
    kstats<<<NBLK_A, 256, 0, stream>>>(spikes, sidx, n);
    kfinal<<<NCLUST, 256, 0, stream>>>();
    kmedian<<<1, 256, 0, stream>>>();
    int nblk = (n + 63) / 64;
    kmatch<<<nblk, 256, 0, stream>>>(spikes, sidx, midx, out, n);
    kprecise<<<64, 256, 0, stream>>>(spikes, out, n);
}

// Round 3
// 1056.825 us; speedup vs baseline: 2.7710x; 1.0350x over previous
//
#include <hip/hip_runtime.h>

#define NCLUST 256      // clusters 1..256 (cluster 0 = CLID_UNMATCHED, excluded)
#define NFEAT  64
#define NBLK_A 512
#define BIGF   1e30f

typedef __attribute__((ext_vector_type(8))) short  short8v;   // 8 x bf16
typedef __attribute__((ext_vector_type(4))) float  float4v;

// ---- static device scratch (rewritten fully every call) ----
__device__ __align__(16) float  g_partials[(size_t)NBLK_A * NCLUST * NFEAT]; // per-block f32 sums
__device__ float  g_pcnt[NBLK_A * NCLUST];
__device__ float  g_pssq[NBLK_A * NCLUST];
__device__ float  g_cnt[NCLUST];
__device__ __align__(16) double g_means64[NCLUST * NFEAT];
__device__ __align__(16) float  g_means32[NCLUST * NFEAT];
__device__ __align__(16) unsigned short g_tmplbf[NCLUST * NFEAT]; // swizzled bf16 templates
__device__ double g_tn64[NCLUST];
__device__ double g_std64[NCLUST];
__device__ float  g_std32[NCLUST];
__device__ float2 g_ktab[NCLUST];         // (tn_f32, thr2_f32 or -1 if invalid)
__device__ int    g_valid[NCLUST];
__device__ int    g_list[1000000];
__device__ int    g_nlist;

static __device__ __forceinline__ unsigned short f2bf(float x) {
    union { float f; unsigned u; } v; v.f = x;
    unsigned r = v.u + 0x7fffu + ((v.u >> 16) & 1u);   // RNE
    return (unsigned short)(r >> 16);
}

// ---------------- Z ----------------
__global__ void kzero() { if (threadIdx.x == 0) g_nlist = 0; }

// ---------------- A: per-block segment sums, NO global atomics ----------------
__global__ __launch_bounds__(256) void kstats(const float* __restrict__ spikes,
                                              const int* __restrict__ sidx, int n) {
    __shared__ float lsum[NCLUST * NFEAT]; // 64 KiB
    __shared__ float lcnt[NCLUST];
    __shared__ float lssq[NCLUST];
    for (int idx = threadIdx.x; idx < NCLUST * NFEAT; idx += 256) lsum[idx] = 0.f;
    if (threadIdx.x < NCLUST) { lcnt[threadIdx.x] = 0.f; lssq[threadIdx.x] = 0.f; }
    __syncthreads();

    const int lane = threadIdx.x & 63;
    const int wave = threadIdx.x >> 6;
    const int per  = (n + gridDim.x - 1) / gridDim.x;
    const int s0   = blockIdx.x * per;
    const int s1   = min(n, s0 + per);

    for (int ib = s0 + wave * 8; ib < s1; ib += 32) {
        float vv[8]; int cc[8];
        #pragma unroll
        for (int j = 0; j < 8; ++j) {
            int i = ib + j;
            bool ok = (i < s1);                       // wave-uniform
            vv[j] = ok ? spikes[(size_t)i * NFEAT + lane] : 0.f;
            cc[j] = ok ? sidx[i] : 0;
        }
        #pragma unroll
        for (int j = 0; j < 8; ++j) {
            float v = vv[j]; int c = cc[j];
            float w = v * v;
            #pragma unroll
            for (int o = 32; o; o >>= 1) w += __shfl_xor(w, o);
            if (c != 0) {
                atomicAdd(&lsum[(c - 1) * NFEAT + lane], v);
                if (lane == 0) {
                    atomicAdd(&lssq[c - 1], w);
                    atomicAdd(&lcnt[c - 1], 1.0f);
                }
            }
        }
    }
    __syncthreads();
    size_t base = (size_t)blockIdx.x * (NCLUST * NFEAT);
    for (int idx = threadIdx.x; idx < NCLUST * NFEAT; idx += 256)
        g_partials[base + idx] = lsum[idx];
    if (threadIdx.x < NCLUST) {
        g_pcnt[blockIdx.x * NCLUST + threadIdx.x] = lcnt[threadIdx.x];
        g_pssq[blockIdx.x * NCLUST + threadIdx.x] = lssq[threadIdx.x];
    }
}

// ---------------- A2: deterministic f64 reduce -> means / cnt / ssq / tn / std ----------------
__global__ __launch_bounds__(256) void kfinal() {
    const int c = blockIdx.x;                 // cluster c+1
    __shared__ double red[4][NFEAT];
    __shared__ double smean[NFEAT];
    __shared__ double sh_cnt, sh_ssq;
    const int f = threadIdx.x & 63, j = threadIdx.x >> 6;

    double acc = 0.0;
    for (int b = j; b < NBLK_A; b += 4)
        acc += (double)g_partials[(size_t)b * (NCLUST * NFEAT) + c * NFEAT + f];
    red[j][f] = acc;

    // cnt/ssq reduce on wave 0 (deterministic tree)
    if (threadIdx.x < 64) {
        double ca = 0.0, sa = 0.0;
        for (int b = threadIdx.x; b < NBLK_A; b += 64) {
            ca += (double)g_pcnt[b * NCLUST + c];
            sa += (double)g_pssq[b * NCLUST + c];
        }
        #pragma unroll
        for (int o = 32; o; o >>= 1) {
            ca += __shfl_xor(ca, o);
            sa += __shfl_xor(sa, o);
        }
        if (threadIdx.x == 0) { sh_cnt = ca; sh_ssq = sa; }
    }
    __syncthreads();

    if (threadIdx.x < NFEAT) {
        double s = ((red[0][f] + red[1][f]) + red[2][f]) + red[3][f];
        double cnt = sh_cnt;
        double mean = (cnt > 0.0) ? s / cnt : 0.0;
        g_means64[c * NFEAT + f] = mean;
        g_means32[c * NFEAT + f] = (float)mean;
        smean[f] = mean;
    }
    __syncthreads();
    if (threadIdx.x == 0) {
        double tn = 0.0;
        for (int q = 0; q < NFEAT; ++q) tn += smean[q] * smean[q];
        double cnt = sh_cnt;
        double var = (cnt > 0.0) ? sh_ssq / cnt - tn : 0.0;
        if (var < 0.0) var = 0.0;
        double sd = sqrt(var);
        g_tn64[c] = tn; g_std64[c] = sd; g_std32[c] = (float)sd;
        g_cnt[c] = (float)cnt;
    }
}

// ---------------- A3: median, validity, thresholds, + bf16 template pre-convert ----------------
__global__ __launch_bounds__(256) void kmedian() {
    __shared__ float svals[NCLUST];
    __shared__ int   svalid[NCLUST];
    __shared__ float mred[2];
    int t = threadIdx.x;
    if (t == 0) { mred[0] = 0.f; mred[1] = 0.f; }
    float cnt = g_cnt[t];
    int v0 = (cnt > 0.f) ? 1 : 0;
    float sd = g_std32[t];
    svals[t] = sd; svalid[t] = v0;
    __syncthreads();

    int m = 0, rank = 0;
    for (int jj = 0; jj < NCLUST; ++jj) {
        if (svalid[jj]) {
            ++m;
            float sj = svals[jj];
            if (sj < sd || (sj == sd && jj < t)) ++rank;
        }
    }
    if (v0) {
        if (rank == (m - 1) / 2) mred[0] = sd;
        if (rank == m / 2)       mred[1] = sd;
    }
    __syncthreads();
    float med = 0.5f * (mred[0] + mred[1]);

    int valid = v0 && (sd <= 3.0f * med);
    double sd64 = g_std64[t];
    float thr2 = valid ? (float)((1.5 * sd64) * (1.5 * sd64)) : -1.0f;
    g_valid[t] = valid;
    g_ktab[t]  = make_float2((float)g_tn64[t], thr2);

    // pre-convert templates to bf16 in the SWIZZLED layout (once, not per kmatch block)
    for (int q = threadIdx.x; q < NCLUST * 8; q += 256) {
        int c = q >> 3, g = q & 7;
        float4 u0 = *(const float4*)&g_means32[c * NFEAT + g * 8];
        float4 u1 = *(const float4*)&g_means32[c * NFEAT + g * 8 + 4];
        short8v h;
        h[0] = (short)f2bf(u0.x); h[1] = (short)f2bf(u0.y);
        h[2] = (short)f2bf(u0.z); h[3] = (short)f2bf(u0.w);
        h[4] = (short)f2bf(u1.x); h[5] = (short)f2bf(u1.y);
        h[6] = (short)f2bf(u1.z); h[7] = (short)f2bf(u1.w);
        unsigned byteoff = (unsigned)c * 128u + (((unsigned)g * 16u) ^ (((unsigned)c & 7u) << 4));
        *(short8v*)((char*)g_tmplbf + byteoff) = h;
    }
}

// ---------------- C: MFMA bulk min pass, 256 spikes per block ----------------
// mfma_f32_16x16x32_bf16: A lane l -> row=l&15, k=(l>>4)*8+j ; B lane l -> col=l&15, same k map.
// D lane l, reg r -> row=(l>>4)*4+r, col=l&15  [verified layout, m89]
__global__ __launch_bounds__(256) void kmatch(const float* __restrict__ spikes,
                                              const int* __restrict__ sidx,
                                              const unsigned char* __restrict__ midx,
                                              float* __restrict__ out, int n) {
    __shared__ __align__(16) unsigned short tml[NCLUST * NFEAT]; // 32 KiB swizzled bf16
    __shared__ float2 ktab_sh[NCLUST];

    // stage pre-swizzled templates: linear 16B copies
    for (int idx = threadIdx.x * 8; idx < NCLUST * NFEAT; idx += 256 * 8)
        *(short8v*)&tml[idx] = *(const short8v*)&g_tmplbf[idx];
    if (threadIdx.x < NCLUST) ktab_sh[threadIdx.x] = g_ktab[threadIdx.x];
    __syncthreads();

    const int lane = threadIdx.x & 63, wave = threadIdx.x >> 6;
    const int row  = lane & 15, grp = lane >> 4;
    const int i0w  = blockIdx.x * 256 + wave * 64;   // this wave's 64 spikes

    #pragma unroll 1
    for (int sb = 0; sb < 4; ++sb) {
        const int i0 = i0w + sb * 16;

        // ---- A fragments (spikes straight from global, f32 -> bf16) ----
        int ri = i0 + row;
        int rc = (ri < n) ? ri : (n - 1);
        const float* sp = spikes + (size_t)rc * NFEAT + grp * 8;
        float4 a0 = *(const float4*)(sp);
        float4 a1 = *(const float4*)(sp + 4);
        float4 a2 = *(const float4*)(sp + 32);
        float4 a3 = *(const float4*)(sp + 36);
        short8v af0, af1;
        af0[0] = (short)f2bf(a0.x); af0[1] = (short)f2bf(a0.y);
        af0[2] = (short)f2bf(a0.z); af0[3] = (short)f2bf(a0.w);
        af0[4] = (short)f2bf(a1.x); af0[5] = (short)f2bf(a1.y);
        af0[6] = (short)f2bf(a1.z); af0[7] = (short)f2bf(a1.w);
        af1[0] = (short)f2bf(a2.x); af1[1] = (short)f2bf(a2.y);
        af1[2] = (short)f2bf(a2.z); af1[3] = (short)f2bf(a2.w);
        af1[4] = (short)f2bf(a3.x); af1[5] = (short)f2bf(a3.y);
        af1[6] = (short)f2bf(a3.z); af1[7] = (short)f2bf(a3.w);

        // sn (|s|^2) in f32 from ORIGINAL f32 values; reduce across the 4 k-groups
        float pss = a0.x*a0.x + a0.y*a0.y + a0.z*a0.z + a0.w*a0.w
                  + a1.x*a1.x + a1.y*a1.y + a1.z*a1.z + a1.w*a1.w
                  + a2.x*a2.x + a2.y*a2.y + a2.z*a2.z + a2.w*a2.w
                  + a3.x*a3.x + a3.y*a3.y + a3.z*a3.z + a3.w*a3.w;
        pss += __shfl_xor(pss, 16);
        pss += __shfl_xor(pss, 32);          // now sn of row `row` on every lane

        float snr[4];
        #pragma unroll
        for (int r = 0; r < 4; ++r) snr[r] = __shfl(pss, grp * 4 + r);

        float d2min[4] = {3.4e38f, 3.4e38f, 3.4e38f, 3.4e38f};

        #pragma unroll 2
        for (int nt = 0; nt < 16; ++nt) {
            int c = nt * 16 + row;
            unsigned co = (unsigned)c * 128u;
            unsigned sw = (((unsigned)c & 7u) << 4);
            short8v b0 = *(short8v*)((char*)tml + (co + (((unsigned)grp * 16u) ^ sw)));
            short8v b1 = *(short8v*)((char*)tml + (co + ((((unsigned)grp + 4u) * 16u) ^ sw)));
            float4v acc = {0.f, 0.f, 0.f, 0.f};
            acc = __builtin_amdgcn_mfma_f32_16x16x32_bf16(af0, b0, acc, 0, 0, 0);
            acc = __builtin_amdgcn_mfma_f32_16x16x32_bf16(af1, b1, acc, 0, 0, 0);
            float2 kt = ktab_sh[c];
            #pragma unroll
            for (int r = 0; r < 4; ++r) {
                float d2 = (snr[r] - 2.0f * acc[r]) + kt.x;
                if (!(d2 > kt.y)) d2min[r] = fminf(d2min[r], d2);  // thr2=-1 => masked
            }
        }

        // min over the 16 cluster-lanes (xor 1,2,4,8)
        #pragma unroll
        for (int o = 1; o < 16; o <<= 1) {
            #pragma unroll
            for (int r = 0; r < 4; ++r) d2min[r] = fminf(d2min[r], __shfl_xor(d2min[r], o));
        }
        if (row == 0) {
            #pragma unroll
            for (int r = 0; r < 4; ++r) {
                int i = i0 + grp * 4 + r;
                if (i < n) {
                    float dm = d2min[r];
                    out[2 * (size_t)n + i] = (dm > 1e37f) ? BIGF : sqrtf(fmaxf(dm, 0.f));
                }
            }
        }
    }

    // pass-through outputs + unmatched list (256 threads cover this block's 256 spikes)
    int i = blockIdx.x * 256 + threadIdx.x;
    if (i < n) {
        int si = sidx[i];
        out[i]             = (float)si;
        out[(size_t)n + i] = midx[i] ? 1.0f : 0.0f;
        if (si == 0) {
            int p = atomicAdd(&g_nlist, 1);
            if (p < 1000000) g_list[p] = i;
        }
    }
}

// ---------------- D: precise f64 argmin for unmatched rows ----------------
// Spike row cached as f32 (exact); converted to f64 inside the FMA. 64 VGPRs
// instead of 128 -> no scratch demotion (R2's 600us bug).
__global__ __launch_bounds__(256, 1) void kprecise(const float* __restrict__ spikes,
                                                   float* __restrict__ out, int n) {
    int nt = g_nlist;
    for (int t = blockIdx.x * blockDim.x + threadIdx.x; t < nt;
         t += gridDim.x * blockDim.x) {
        int i = g_list[t];
        float sf[NFEAT];
        const float4* sp4 = (const float4*)(spikes + (size_t)i * NFEAT);
        #pragma unroll
        for (int q = 0; q < 16; ++q) *(float4*)&sf[q * 4] = sp4[q];

        double sn = 0.0;
        #pragma unroll
        for (int f = 0; f < NFEAT; ++f) { double d = (double)sf[f]; sn += d * d; }

        double dmin = 1e30; int best = 0;
        for (int k = 0; k < NCLUST; ++k) {
            if (!g_valid[k]) continue;
            const double* mk = &g_means64[k * NFEAT];
            double dot = 0.0;
            #pragma unroll
            for (int f = 0; f < NFEAT; ++f) dot += (double)sf[f] * mk[f];
            double d2 = (sn - 2.0 * dot) + g_tn64[k];
            double dist = sqrt(fmax(d2, 0.0));
            if (dist > 1.5 * g_std64[k]) continue;
            if (dist < dmin) { dmin = dist; best = k + 1; }   // ascending k => first-index ties
        }
        if (dmin >= 256.0) best = 0;   // FIRST_MATCH_MAX_DIST * N_SAMPLES
        out[i]                 = (float)best;
        out[(size_t)n + i]     = (best != 0) ? 1.0f : 0.0f;
        out[2 * (size_t)n + i] = (float)dmin;
    }
}

extern "C" void kernel_launch(void* const* d_in, const int* in_sizes, int n_in,
                              void* d_out, int out_size, void* d_ws, size_t ws_size,
                              hipStream_t stream) {
    const float*         spikes = (const float*)d_in[0];
    const int*           sidx   = (const int*)d_in[1];
    const unsigned char* midx   = (const unsigned char*)d_in[2];
    float*               out    = (float*)d_out;
    const int n = in_sizes[1];

    kzero<<<1, 64, 0, stream>>>();
    kstats<<<NBLK_A, 256, 0, stream>>>(spikes, sidx, n);
    kfinal<<<NCLUST, 256, 0, stream>>>();
    kmedian<<<1, 256, 0, stream>>>();
    int nblk = (n + 255) / 256;
    kmatch<<<nblk, 256, 0, stream>>>(spikes, sidx, midx, out, n);
    kprecise<<<64, 256, 0, stream>>>(spikes, out, n);
}

// Round 4
// 730.048 us; speedup vs baseline: 4.0114x; 1.4476x over previous
//
#include <hip/hip_runtime.h>

#define NCLUST 256      // clusters 1..256 (cluster 0 = CLID_UNMATCHED, excluded)
#define NFEAT  64
#define NBLK_A 512
#define BIGF   1e30f

typedef __attribute__((ext_vector_type(8))) short  short8v;   // 8 x bf16
typedef __attribute__((ext_vector_type(4))) float  float4v;

// ---- static device scratch (rewritten fully every call) ----
__device__ __align__(16) float  g_partials[(size_t)NBLK_A * NCLUST * NFEAT]; // per-block f32 sums
__device__ float  g_pcnt[NBLK_A * NCLUST];
__device__ float  g_pssq[NBLK_A * NCLUST];
__device__ float  g_cnt[NCLUST];
__device__ __align__(16) double g_means64[NCLUST * NFEAT];
__device__ __align__(16) float  g_means32[NCLUST * NFEAT];
__device__ __align__(16) unsigned short g_tmplbf[NCLUST * NFEAT]; // swizzled bf16 templates
__device__ double g_tn64[NCLUST];
__device__ double g_std64[NCLUST];
__device__ float  g_std32[NCLUST];
__device__ float2 g_ktab[NCLUST];         // (tn_f32, thr2_f32 or -1 if invalid)
__device__ int    g_valid[NCLUST];
__device__ int    g_list[1000000];
__device__ int    g_nlist;

static __device__ __forceinline__ unsigned short f2bf(float x) {
    union { float f; unsigned u; } v; v.f = x;
    unsigned r = v.u + 0x7fffu + ((v.u >> 16) & 1u);   // RNE
    return (unsigned short)(r >> 16);
}

// ---------------- Z ----------------
__global__ void kzero() { if (threadIdx.x == 0) g_nlist = 0; }

// ---------------- A: per-block segment sums, NO global atomics ----------------
__global__ __launch_bounds__(256) void kstats(const float* __restrict__ spikes,
                                              const int* __restrict__ sidx, int n) {
    __shared__ float lsum[NCLUST * NFEAT]; // 64 KiB
    __shared__ float lcnt[NCLUST];
    __shared__ float lssq[NCLUST];
    for (int idx = threadIdx.x; idx < NCLUST * NFEAT; idx += 256) lsum[idx] = 0.f;
    if (threadIdx.x < NCLUST) { lcnt[threadIdx.x] = 0.f; lssq[threadIdx.x] = 0.f; }
    __syncthreads();

    const int lane = threadIdx.x & 63;
    const int wave = threadIdx.x >> 6;
    const int per  = (n + gridDim.x - 1) / gridDim.x;
    const int s0   = blockIdx.x * per;
    const int s1   = min(n, s0 + per);

    for (int ib = s0 + wave * 8; ib < s1; ib += 32) {
        float vv[8]; int cc[8];
        #pragma unroll
        for (int j = 0; j < 8; ++j) {
            int i = ib + j;
            bool ok = (i < s1);                       // wave-uniform
            vv[j] = ok ? spikes[(size_t)i * NFEAT + lane] : 0.f;
            cc[j] = ok ? sidx[i] : 0;
        }
        #pragma unroll
        for (int j = 0; j < 8; ++j) {
            float v = vv[j]; int c = cc[j];
            float w = v * v;
            #pragma unroll
            for (int o = 32; o; o >>= 1) w += __shfl_xor(w, o);
            if (c != 0) {
                atomicAdd(&lsum[(c - 1) * NFEAT + lane], v);
                if (lane == 0) {
                    atomicAdd(&lssq[c - 1], w);
                    atomicAdd(&lcnt[c - 1], 1.0f);
                }
            }
        }
    }
    __syncthreads();
    size_t base = (size_t)blockIdx.x * (NCLUST * NFEAT);
    for (int idx = threadIdx.x; idx < NCLUST * NFEAT; idx += 256)
        g_partials[base + idx] = lsum[idx];
    if (threadIdx.x < NCLUST) {
        g_pcnt[blockIdx.x * NCLUST + threadIdx.x] = lcnt[threadIdx.x];
        g_pssq[blockIdx.x * NCLUST + threadIdx.x] = lssq[threadIdx.x];
    }
}

// ---------------- A2: deterministic f64 reduce -> means / cnt / ssq / tn / std ----------------
__global__ __launch_bounds__(256) void kfinal() {
    const int c = blockIdx.x;                 // cluster c+1
    __shared__ double red[4][NFEAT];
    __shared__ double smean[NFEAT];
    __shared__ double sh_cnt, sh_ssq;
    const int f = threadIdx.x & 63, j = threadIdx.x >> 6;

    double acc = 0.0;
    for (int b = j; b < NBLK_A; b += 4)
        acc += (double)g_partials[(size_t)b * (NCLUST * NFEAT) + c * NFEAT + f];
    red[j][f] = acc;

    // cnt/ssq reduce on wave 0 (deterministic tree)
    if (threadIdx.x < 64) {
        double ca = 0.0, sa = 0.0;
        for (int b = threadIdx.x; b < NBLK_A; b += 64) {
            ca += (double)g_pcnt[b * NCLUST + c];
            sa += (double)g_pssq[b * NCLUST + c];
        }
        #pragma unroll
        for (int o = 32; o; o >>= 1) {
            ca += __shfl_xor(ca, o);
            sa += __shfl_xor(sa, o);
        }
        if (threadIdx.x == 0) { sh_cnt = ca; sh_ssq = sa; }
    }
    __syncthreads();

    if (threadIdx.x < NFEAT) {
        double s = ((red[0][f] + red[1][f]) + red[2][f]) + red[3][f];
        double cnt = sh_cnt;
        double mean = (cnt > 0.0) ? s / cnt : 0.0;
        g_means64[c * NFEAT + f] = mean;
        g_means32[c * NFEAT + f] = (float)mean;
        smean[f] = mean;
    }
    __syncthreads();
    if (threadIdx.x == 0) {
        double tn = 0.0;
        for (int q = 0; q < NFEAT; ++q) tn += smean[q] * smean[q];
        double cnt = sh_cnt;
        double var = (cnt > 0.0) ? sh_ssq / cnt - tn : 0.0;
        if (var < 0.0) var = 0.0;
        double sd = sqrt(var);
        g_tn64[c] = tn; g_std64[c] = sd; g_std32[c] = (float)sd;
        g_cnt[c] = (float)cnt;
    }
}

// ---------------- A3: median, validity, thresholds, + bf16 template pre-convert ----------------
__global__ __launch_bounds__(256) void kmedian() {
    __shared__ float svals[NCLUST];
    __shared__ int   svalid[NCLUST];
    __shared__ float mred[2];
    int t = threadIdx.x;
    if (t == 0) { mred[0] = 0.f; mred[1] = 0.f; }
    float cnt = g_cnt[t];
    int v0 = (cnt > 0.f) ? 1 : 0;
    float sd = g_std32[t];
    svals[t] = sd; svalid[t] = v0;
    __syncthreads();

    int m = 0, rank = 0;
    for (int jj = 0; jj < NCLUST; ++jj) {
        if (svalid[jj]) {
            ++m;
            float sj = svals[jj];
            if (sj < sd || (sj == sd && jj < t)) ++rank;
        }
    }
    if (v0) {
        if (rank == (m - 1) / 2) mred[0] = sd;
        if (rank == m / 2)       mred[1] = sd;
    }
    __syncthreads();
    float med = 0.5f * (mred[0] + mred[1]);

    int valid = v0 && (sd <= 3.0f * med);
    double sd64 = g_std64[t];
    float thr2 = valid ? (float)((1.5 * sd64) * (1.5 * sd64)) : -1.0f;
    g_valid[t] = valid;
    g_ktab[t]  = make_float2((float)g_tn64[t], thr2);

    // pre-convert templates to bf16 in the SWIZZLED layout (once, not per kmatch block)
    for (int q = threadIdx.x; q < NCLUST * 8; q += 256) {
        int c = q >> 3, g = q & 7;
        float4 u0 = *(const float4*)&g_means32[c * NFEAT + g * 8];
        float4 u1 = *(const float4*)&g_means32[c * NFEAT + g * 8 + 4];
        short8v h;
        h[0] = (short)f2bf(u0.x); h[1] = (short)f2bf(u0.y);
        h[2] = (short)f2bf(u0.z); h[3] = (short)f2bf(u0.w);
        h[4] = (short)f2bf(u1.x); h[5] = (short)f2bf(u1.y);
        h[6] = (short)f2bf(u1.z); h[7] = (short)f2bf(u1.w);
        unsigned byteoff = (unsigned)c * 128u + (((unsigned)g * 16u) ^ (((unsigned)c & 7u) << 4));
        *(short8v*)((char*)g_tmplbf + byteoff) = h;
    }
}

// ---------------- C: MFMA bulk min pass, 256 spikes per block ----------------
// mfma_f32_16x16x32_bf16: A lane l -> row=l&15, k=(l>>4)*8+j ; B lane l -> col=l&15, same k map.
// D lane l, reg r -> row=(l>>4)*4+r, col=l&15  [verified layout, m89]
__global__ __launch_bounds__(256) void kmatch(const float* __restrict__ spikes,
                                              const int* __restrict__ sidx,
                                              const unsigned char* __restrict__ midx,
                                              float* __restrict__ out, int n) {
    __shared__ __align__(16) unsigned short tml[NCLUST * NFEAT]; // 32 KiB swizzled bf16
    __shared__ float2 ktab_sh[NCLUST];

    // stage pre-swizzled templates: linear 16B copies
    for (int idx = threadIdx.x * 8; idx < NCLUST * NFEAT; idx += 256 * 8)
        *(short8v*)&tml[idx] = *(const short8v*)&g_tmplbf[idx];
    if (threadIdx.x < NCLUST) ktab_sh[threadIdx.x] = g_ktab[threadIdx.x];
    __syncthreads();

    const int lane = threadIdx.x & 63, wave = threadIdx.x >> 6;
    const int row  = lane & 15, grp = lane >> 4;
    const int i0w  = blockIdx.x * 256 + wave * 64;   // this wave's 64 spikes

    #pragma unroll 1
    for (int sb = 0; sb < 4; ++sb) {
        const int i0 = i0w + sb * 16;

        // ---- A fragments (spikes straight from global, f32 -> bf16) ----
        int ri = i0 + row;
        int rc = (ri < n) ? ri : (n - 1);
        const float* sp = spikes + (size_t)rc * NFEAT + grp * 8;
        float4 a0 = *(const float4*)(sp);
        float4 a1 = *(const float4*)(sp + 4);
        float4 a2 = *(const float4*)(sp + 32);
        float4 a3 = *(const float4*)(sp + 36);
        short8v af0, af1;
        af0[0] = (short)f2bf(a0.x); af0[1] = (short)f2bf(a0.y);
        af0[2] = (short)f2bf(a0.z); af0[3] = (short)f2bf(a0.w);
        af0[4] = (short)f2bf(a1.x); af0[5] = (short)f2bf(a1.y);
        af0[6] = (short)f2bf(a1.z); af0[7] = (short)f2bf(a1.w);
        af1[0] = (short)f2bf(a2.x); af1[1] = (short)f2bf(a2.y);
        af1[2] = (short)f2bf(a2.z); af1[3] = (short)f2bf(a2.w);
        af1[4] = (short)f2bf(a3.x); af1[5] = (short)f2bf(a3.y);
        af1[6] = (short)f2bf(a3.z); af1[7] = (short)f2bf(a3.w);

        // sn (|s|^2) in f32 from ORIGINAL f32 values; reduce across the 4 k-groups
        float pss = a0.x*a0.x + a0.y*a0.y + a0.z*a0.z + a0.w*a0.w
                  + a1.x*a1.x + a1.y*a1.y + a1.z*a1.z + a1.w*a1.w
                  + a2.x*a2.x + a2.y*a2.y + a2.z*a2.z + a2.w*a2.w
                  + a3.x*a3.x + a3.y*a3.y + a3.z*a3.z + a3.w*a3.w;
        pss += __shfl_xor(pss, 16);
        pss += __shfl_xor(pss, 32);          // now sn of row `row` on every lane

        float snr[4];
        #pragma unroll
        for (int r = 0; r < 4; ++r) snr[r] = __shfl(pss, grp * 4 + r);

        float d2min[4] = {3.4e38f, 3.4e38f, 3.4e38f, 3.4e38f};

        #pragma unroll 2
        for (int nt = 0; nt < 16; ++nt) {
            int c = nt * 16 + row;
            unsigned co = (unsigned)c * 128u;
            unsigned sw = (((unsigned)c & 7u) << 4);
            short8v b0 = *(short8v*)((char*)tml + (co + (((unsigned)grp * 16u) ^ sw)));
            short8v b1 = *(short8v*)((char*)tml + (co + ((((unsigned)grp + 4u) * 16u) ^ sw)));
            float4v acc = {0.f, 0.f, 0.f, 0.f};
            acc = __builtin_amdgcn_mfma_f32_16x16x32_bf16(af0, b0, acc, 0, 0, 0);
            acc = __builtin_amdgcn_mfma_f32_16x16x32_bf16(af1, b1, acc, 0, 0, 0);
            float2 kt = ktab_sh[c];
            #pragma unroll
            for (int r = 0; r < 4; ++r) {
                float d2 = (snr[r] - 2.0f * acc[r]) + kt.x;
                if (!(d2 > kt.y)) d2min[r] = fminf(d2min[r], d2);  // thr2=-1 => masked
            }
        }

        // min over the 16 cluster-lanes (xor 1,2,4,8)
        #pragma unroll
        for (int o = 1; o < 16; o <<= 1) {
            #pragma unroll
            for (int r = 0; r < 4; ++r) d2min[r] = fminf(d2min[r], __shfl_xor(d2min[r], o));
        }
        if (row == 0) {
            #pragma unroll
            for (int r = 0; r < 4; ++r) {
                int i = i0 + grp * 4 + r;
                if (i < n) {
                    float dm = d2min[r];
                    out[2 * (size_t)n + i] = (dm > 1e37f) ? BIGF : sqrtf(fmaxf(dm, 0.f));
                }
            }
        }
    }

    // pass-through outputs + unmatched list (256 threads cover this block's 256 spikes)
    int i = blockIdx.x * 256 + threadIdx.x;
    if (i < n) {
        int si = sidx[i];
        out[i]             = (float)si;
        out[(size_t)n + i] = midx[i] ? 1.0f : 0.0f;
        if (si == 0) {
            int p = atomicAdd(&g_nlist, 1);
            if (p < 1000000) g_list[p] = i;
        }
    }
}

// ---------------- D: precise f64 argmin, WAVE-PER-SPIKE (lane = feature) ----------------
// No per-thread array -> nothing for the allocator to demote (R3 bug: sf[64]
// went to scratch at 0.75% occupancy -> 600us). Lane f holds one scalar;
// dot(k) = butterfly-reduce(sf * means64[k][f]); clusters processed in pairs for ILP.
__global__ __launch_bounds__(256) void kprecise(const float* __restrict__ spikes,
                                                float* __restrict__ out, int n) {
    const int lane  = threadIdx.x & 63;
    const int gwave = (blockIdx.x * 256 + threadIdx.x) >> 6;
    const int nwave = (gridDim.x * 256) >> 6;
    const int nt    = g_nlist;

    for (int t = gwave; t < nt; t += nwave) {
        const int i = g_list[t];
        const double sf = (double)spikes[(size_t)i * NFEAT + lane];

        double sn = sf * sf;
        #pragma unroll
        for (int o = 32; o; o >>= 1) sn += __shfl_xor(sn, o);

        double dmin = 1e30; int best = 0;
        #pragma unroll 1
        for (int k = 0; k < NCLUST; k += 2) {
            double p0 = sf * g_means64[(size_t)(k + 0) * NFEAT + lane];
            double p1 = sf * g_means64[(size_t)(k + 1) * NFEAT + lane];
            #pragma unroll
            for (int o = 32; o; o >>= 1) {
                p0 += __shfl_xor(p0, o);
                p1 += __shfl_xor(p1, o);
            }
            #pragma unroll
            for (int j = 0; j < 2; ++j) {
                const int kk = k + j;
                const double dot = j ? p1 : p0;
                if (!g_valid[kk]) continue;
                double d2 = (sn - 2.0 * dot) + g_tn64[kk];
                double dist = sqrt(fmax(d2, 0.0));
                if (dist > 1.5 * g_std64[kk]) continue;
                if (dist < dmin) { dmin = dist; best = kk + 1; }  // ascending k => first-index ties
            }
        }
        if (dmin >= 256.0) best = 0;   // FIRST_MATCH_MAX_DIST * N_SAMPLES

        if (lane == 0) {
            out[i]                 = (float)best;
            out[(size_t)n + i]     = (best != 0) ? 1.0f : 0.0f;
            out[2 * (size_t)n + i] = (float)dmin;
        }
    }
}

extern "C" void kernel_launch(void* const* d_in, const int* in_sizes, int n_in,
                              void* d_out, int out_size, void* d_ws, size_t ws_size,
                              hipStream_t stream) {
    const float*         spikes = (const float*)d_in[0];
    const int*           sidx   = (const int*)d_in[1];
    const unsigned char* midx   = (const unsigned char*)d_in[2];
    float*               out    = (float*)d_out;
    const int n = in_sizes[1];

    kzero<<<1, 64, 0, stream>>>();
    kstats<<<NBLK_A, 256, 0, stream>>>(spikes, sidx, n);
    kfinal<<<NCLUST, 256, 0, stream>>>();
    kmedian<<<1, 256, 0, stream>>>();
    int nblk = (n + 255) / 256;
    kmatch<<<nblk, 256, 0, stream>>>(spikes, sidx, midx, out, n);
    kprecise<<<1024, 256, 0, stream>>>(spikes, out, n);
}